// Round 3
// baseline (1533.922 us; speedup 1.0000x reference)
//
#include <hip/hip_runtime.h>

// out = L @ features, L in COO. Coarse counting-sort into buckets of 256
// consecutive destination rows, then per-bucket LDS accumulation (64KB acc),
// one coalesced store per bucket. No global float atomics, no fine sort.
//
// ws: gcnt[NB] | bptr[NB+1] | cursor[NB] | pad | edges[nnz] (int2: packed, val)
// packed.x = (row_local<<17) | col   (needs n_nodes < 2^17)

#define DFEAT 64
#define RPB 256            // rows per bucket (LDS acc = 256*64*4 = 64KB)
#define EPT 8              // edges per thread in hist/scatter
#define SBLK 512           // hist/scatter block size

__global__ __launch_bounds__(SBLK) void hist_bucket(
    const int* __restrict__ rows, int* __restrict__ gcnt, int nnz, int nb)
{
    extern __shared__ int lcnt[];
    for (int i = threadIdx.x; i < nb; i += blockDim.x) lcnt[i] = 0;
    __syncthreads();
    const int base = blockIdx.x * (SBLK * EPT);
    #pragma unroll
    for (int k = 0; k < EPT; ++k) {
        int e = base + k * SBLK + threadIdx.x;
        if (e < nnz) atomicAdd(&lcnt[rows[e] >> 8], 1);
    }
    __syncthreads();
    for (int i = threadIdx.x; i < nb; i += blockDim.x) {
        int c = lcnt[i];
        if (c) atomicAdd(&gcnt[i], c);
    }
}

__global__ __launch_bounds__(1024) void scan_small(
    const int* __restrict__ gcnt, int* __restrict__ bptr,
    int* __restrict__ cursor, int nb)
{
    __shared__ int sh[1024];
    int t = threadIdx.x;
    int v = (t < nb) ? gcnt[t] : 0;
    sh[t] = v;
    __syncthreads();
    for (int d = 1; d < 1024; d <<= 1) {
        int u = (t >= d) ? sh[t - d] : 0;
        __syncthreads();
        sh[t] += u;
        __syncthreads();
    }
    if (t < nb) {
        int ex = sh[t] - v;
        bptr[t] = ex;
        cursor[t] = ex;
    }
    if (t == nb - 1) bptr[nb] = sh[t];
}

__global__ __launch_bounds__(SBLK) void scatter_bucket(
    const int* __restrict__ rows, const int* __restrict__ cols,
    const float* __restrict__ vals, int* __restrict__ cursor,
    int2* __restrict__ eout, int nnz, int nb)
{
    extern __shared__ int sh[];
    int* lcnt  = sh;       // [nb]
    int* lbase = sh + nb;  // [nb]
    for (int i = threadIdx.x; i < nb; i += blockDim.x) lcnt[i] = 0;
    __syncthreads();

    const int base = blockIdx.x * (SBLK * EPT);
    int r[EPT], c[EPT], loff[EPT];
    float v[EPT];
    #pragma unroll
    for (int k = 0; k < EPT; ++k) {
        int e = base + k * SBLK + threadIdx.x;
        bool ok = (e < nnz);
        r[k] = ok ? rows[e] : -1;
        c[k] = ok ? cols[e] : 0;
        v[k] = ok ? vals[e] : 0.f;
        loff[k] = ok ? atomicAdd(&lcnt[r[k] >> 8], 1) : 0;
    }
    __syncthreads();
    for (int i = threadIdx.x; i < nb; i += blockDim.x) {
        int cc = lcnt[i];
        lbase[i] = cc ? atomicAdd(&cursor[i], cc) : 0;
    }
    __syncthreads();
    #pragma unroll
    for (int k = 0; k < EPT; ++k) {
        if (r[k] >= 0) {
            int b = r[k] >> 8;
            int pos = lbase[b] + loff[k];
            eout[pos] = make_int2(((r[k] & 255) << 17) | c[k],
                                  __float_as_int(v[k]));
        }
    }
}

// One block per bucket of 256 rows; 64KB LDS accumulator; 8 waves stream edges.
__global__ __launch_bounds__(512) void spmm_bucket(
    const float* __restrict__ features, const int2* __restrict__ eout,
    const int* __restrict__ bptr, float* __restrict__ out, int n)
{
    __shared__ float acc[RPB * DFEAT];  // 64KB
    for (int i = threadIdx.x; i < RPB * DFEAT; i += blockDim.x) acc[i] = 0.f;
    __syncthreads();

    const int b    = blockIdx.x;
    const int beg  = bptr[b];
    const int end  = bptr[b + 1];
    const int lane = threadIdx.x & 63;
    const int wid  = threadIdx.x >> 6;  // 0..7

    for (int gbase = beg + wid * 64; gbase < end; gbase += 8 * 64) {
        int m = end - gbase;
        if (m > 64) m = 64;
        int px = 0, py = 0;
        if (gbase + lane < end) {
            int2 e = eout[gbase + lane];  // coalesced cooperative edge load
            px = e.x;
            py = e.y;
        }
        for (int j = 0; j < m; ++j) {
            int   ex = __shfl(px, j);
            float ev = __int_as_float(__shfl(py, j));
            int col = ex & 0x1FFFF;
            int rl  = ex >> 17;
            float f = features[(size_t)col * DFEAT + lane];  // 256B coalesced
            atomicAdd(&acc[rl * DFEAT + lane], ev * f);      // ds_add_f32, 2-way bank (free)
        }
    }
    __syncthreads();

    const int row0 = b * RPB;
    int rows_here = n - row0;
    if (rows_here > RPB) rows_here = RPB;
    float* op = out + (size_t)row0 * DFEAT;
    for (int i = threadIdx.x; i < rows_here * DFEAT; i += blockDim.x)
        op[i] = acc[i];  // coalesced 64KB store
}

// ---- fallback: direct atomic scatter-add (round-1 kernel) ----
__global__ __launch_bounds__(256) void spmm_coo_atomic(
    const float* __restrict__ features, const int* __restrict__ rows,
    const int* __restrict__ cols, const float* __restrict__ vals,
    float* __restrict__ out, int nnz)
{
    long long t = (long long)blockIdx.x * blockDim.x + threadIdx.x;
    long long e = t >> 4;
    if (e >= nnz) return;
    int c = ((int)t & 15) << 2;
    int row = rows[e], col = cols[e];
    float v = vals[e];
    const float4 f = *reinterpret_cast<const float4*>(features + (size_t)col * DFEAT + c);
    float* op = out + (size_t)row * DFEAT + c;
    atomicAdd(op + 0, v * f.x);
    atomicAdd(op + 1, v * f.y);
    atomicAdd(op + 2, v * f.z);
    atomicAdd(op + 3, v * f.w);
}

extern "C" void kernel_launch(void* const* d_in, const int* in_sizes, int n_in,
                              void* d_out, int out_size, void* d_ws, size_t ws_size,
                              hipStream_t stream) {
    const float* features = (const float*)d_in[0];
    const int*   rows     = (const int*)  d_in[1];
    const int*   cols     = (const int*)  d_in[2];
    const float* vals     = (const float*)d_in[3];
    float*       out      = (float*)      d_out;
    const int    nnz      = in_sizes[1];
    const int    n_nodes  = in_sizes[0] / DFEAT;
    const int    nb       = (n_nodes + RPB - 1) / RPB;

    // ws layout
    char*  base       = (char*)d_ws;
    size_t off_gcnt   = 0;
    size_t off_bptr   = off_gcnt + (size_t)nb * 4;
    size_t off_cursor = off_bptr + ((size_t)nb + 1) * 4;
    size_t off_edges  = (off_cursor + (size_t)nb * 4 + 7) & ~(size_t)7;
    size_t need       = off_edges + (size_t)nnz * 8;

    if (ws_size < need || nb > 1024 || n_nodes >= (1 << 17)) {
        hipMemsetAsync(d_out, 0, (size_t)out_size * sizeof(float), stream);
        const long long tt = (long long)nnz * 16;
        spmm_coo_atomic<<<(unsigned)((tt + 255) / 256), 256, 0, stream>>>(
            features, rows, cols, vals, out, nnz);
        return;
    }

    int*  gcnt   = (int*) (base + off_gcnt);
    int*  bptr   = (int*) (base + off_bptr);
    int*  cursor = (int*) (base + off_cursor);
    int2* edges  = (int2*)(base + off_edges);

    hipMemsetAsync(gcnt, 0, (size_t)nb * 4, stream);

    const int eb = (nnz + SBLK * EPT - 1) / (SBLK * EPT);
    hist_bucket<<<eb, SBLK, nb * 4, stream>>>(rows, gcnt, nnz, nb);
    scan_small<<<1, 1024, 0, stream>>>(gcnt, bptr, cursor, nb);
    scatter_bucket<<<eb, SBLK, 2 * nb * 4, stream>>>(
        rows, cols, vals, cursor, edges, nnz, nb);
    spmm_bucket<<<nb, 512, 0, stream>>>(features, edges, bptr, out, n_nodes);
}

// Round 4
// 1426.810 us; speedup vs baseline: 1.0751x; 1.0751x over previous
//
#include <hip/hip_runtime.h>

// out = L @ features, L in COO. Coarse counting-sort into buckets of 128
// consecutive destination rows, then per-bucket LDS accumulation (padded
// 34KB acc), quarter-wave-per-edge float4 gathers (4 edge streams/wave,
// no shfl), one coalesced store per bucket. No global float atomics.
//
// ws: gcnt[NB] | bptr[NB+1] | cursor[NB] | pad | edges[nnz] (int2)
// packed.x = (row_local<<17) | col   (needs n_nodes < 2^17, RPB <= 128)

#define DFEAT 64
#define RPB 128            // rows per bucket
#define STR 68             // padded LDS row stride (floats): rotates bank phase
#define EPT 8              // edges per thread in hist/scatter
#define SBLK 512           // hist/scatter block size

__global__ __launch_bounds__(SBLK) void hist_bucket(
    const int* __restrict__ rows, int* __restrict__ gcnt, int nnz, int nb)
{
    extern __shared__ int lcnt[];
    for (int i = threadIdx.x; i < nb; i += blockDim.x) lcnt[i] = 0;
    __syncthreads();
    const int base = blockIdx.x * (SBLK * EPT);
    #pragma unroll
    for (int k = 0; k < EPT; ++k) {
        int e = base + k * SBLK + threadIdx.x;
        if (e < nnz) atomicAdd(&lcnt[rows[e] >> 7], 1);
    }
    __syncthreads();
    for (int i = threadIdx.x; i < nb; i += blockDim.x) {
        int c = lcnt[i];
        if (c) atomicAdd(&gcnt[i], c);
    }
}

__global__ __launch_bounds__(1024) void scan_small(
    const int* __restrict__ gcnt, int* __restrict__ bptr,
    int* __restrict__ cursor, int nb)
{
    __shared__ int sh[1024];
    int t = threadIdx.x;
    int v = (t < nb) ? gcnt[t] : 0;
    sh[t] = v;
    __syncthreads();
    for (int d = 1; d < 1024; d <<= 1) {
        int u = (t >= d) ? sh[t - d] : 0;
        __syncthreads();
        sh[t] += u;
        __syncthreads();
    }
    if (t < nb) {
        int ex = sh[t] - v;
        bptr[t] = ex;
        cursor[t] = ex;
    }
    if (t == nb - 1) bptr[nb] = sh[t];
}

__global__ __launch_bounds__(SBLK) void scatter_bucket(
    const int* __restrict__ rows, const int* __restrict__ cols,
    const float* __restrict__ vals, int* __restrict__ cursor,
    int2* __restrict__ eout, int nnz, int nb)
{
    extern __shared__ int sh[];
    int* lcnt  = sh;       // [nb]
    int* lbase = sh + nb;  // [nb]
    for (int i = threadIdx.x; i < nb; i += blockDim.x) lcnt[i] = 0;
    __syncthreads();

    const int base = blockIdx.x * (SBLK * EPT);
    int r[EPT], c[EPT], loff[EPT];
    float v[EPT];
    #pragma unroll
    for (int k = 0; k < EPT; ++k) {
        int e = base + k * SBLK + threadIdx.x;
        bool ok = (e < nnz);
        r[k] = ok ? rows[e] : -1;
        c[k] = ok ? cols[e] : 0;
        v[k] = ok ? vals[e] : 0.f;
        loff[k] = ok ? atomicAdd(&lcnt[r[k] >> 7], 1) : 0;
    }
    __syncthreads();
    for (int i = threadIdx.x; i < nb; i += blockDim.x) {
        int cc = lcnt[i];
        lbase[i] = cc ? atomicAdd(&cursor[i], cc) : 0;
    }
    __syncthreads();
    #pragma unroll
    for (int k = 0; k < EPT; ++k) {
        if (r[k] >= 0) {
            int b = r[k] >> 7;
            int pos = lbase[b] + loff[k];
            eout[pos] = make_int2(((r[k] & 127) << 17) | c[k],
                                  __float_as_int(v[k]));
        }
    }
}

// One block per bucket of 128 rows; 34KB padded LDS accumulator.
// Quarter-wave (16 lanes) per edge, float4 per lane: 4 independent edge
// streams per wave + explicit next-edge prefetch for MLP. No shfl.
__global__ __launch_bounds__(512) void spmm_bucket2(
    const float* __restrict__ features, const int2* __restrict__ eout,
    const int* __restrict__ bptr, float* __restrict__ out, int n)
{
    __shared__ float acc[RPB * STR];  // 34,816 B -> 4 blocks/CU
    for (int i = threadIdx.x; i < RPB * STR; i += 512) acc[i] = 0.f;
    __syncthreads();

    const int b    = blockIdx.x;
    const int beg  = bptr[b];
    const int end  = bptr[b + 1];
    const int lane = threadIdx.x & 63;
    const int wid  = threadIdx.x >> 6;   // 0..7
    const int sub  = lane >> 4;          // quarter-wave 0..3
    const int fo   = (lane & 15) << 2;   // float offset in row: 0,4,...,60

    int e = beg + wid * 4 + sub;
    if (e < end) {
        int2 ed = eout[e];               // 16 lanes same addr -> broadcast
        for (;;) {
            const int  en   = e + 32;    // 8 waves x 4 edges
            const bool more = (en < end);
            int2 edn;
            if (more) edn = eout[en];    // prefetch next edge record

            const int   col = ed.x & 0x1FFFF;
            const int   rl  = ed.x >> 17;
            const float v   = __int_as_float(ed.y);
            const float4 f  = *reinterpret_cast<const float4*>(
                features + (size_t)col * DFEAT + fo);  // 256B/edge coalesced
            float* ap = acc + rl * STR + fo;
            atomicAdd(ap + 0, v * f.x);  // ds_add_f32; stride-68 rotates
            atomicAdd(ap + 1, v * f.y);  // bank phase per row -> ~2-way
            atomicAdd(ap + 2, v * f.z);
            atomicAdd(ap + 3, v * f.w);

            if (!more) break;
            e = en;
            ed = edn;
        }
    }
    __syncthreads();

    const int row0 = b * RPB;
    int rows_here = n - row0;
    if (rows_here > RPB) rows_here = RPB;
    float* op = out + (size_t)row0 * DFEAT;
    for (int i = threadIdx.x; i < rows_here * DFEAT; i += 512) {
        int r = i >> 6, d = i & 63;
        op[i] = acc[r * STR + d];        // coalesced store
    }
}

// ---- fallback: direct atomic scatter-add (round-1 kernel) ----
__global__ __launch_bounds__(256) void spmm_coo_atomic(
    const float* __restrict__ features, const int* __restrict__ rows,
    const int* __restrict__ cols, const float* __restrict__ vals,
    float* __restrict__ out, int nnz)
{
    long long t = (long long)blockIdx.x * blockDim.x + threadIdx.x;
    long long e = t >> 4;
    if (e >= nnz) return;
    int c = ((int)t & 15) << 2;
    int row = rows[e], col = cols[e];
    float v = vals[e];
    const float4 f = *reinterpret_cast<const float4*>(features + (size_t)col * DFEAT + c);
    float* op = out + (size_t)row * DFEAT + c;
    atomicAdd(op + 0, v * f.x);
    atomicAdd(op + 1, v * f.y);
    atomicAdd(op + 2, v * f.z);
    atomicAdd(op + 3, v * f.w);
}

extern "C" void kernel_launch(void* const* d_in, const int* in_sizes, int n_in,
                              void* d_out, int out_size, void* d_ws, size_t ws_size,
                              hipStream_t stream) {
    const float* features = (const float*)d_in[0];
    const int*   rows     = (const int*)  d_in[1];
    const int*   cols     = (const int*)  d_in[2];
    const float* vals     = (const float*)d_in[3];
    float*       out      = (float*)      d_out;
    const int    nnz      = in_sizes[1];
    const int    n_nodes  = in_sizes[0] / DFEAT;
    const int    nb       = (n_nodes + RPB - 1) / RPB;

    // ws layout
    char*  base       = (char*)d_ws;
    size_t off_gcnt   = 0;
    size_t off_bptr   = off_gcnt + (size_t)nb * 4;
    size_t off_cursor = off_bptr + ((size_t)nb + 1) * 4;
    size_t off_edges  = (off_cursor + (size_t)nb * 4 + 7) & ~(size_t)7;
    size_t need       = off_edges + (size_t)nnz * 8;

    if (ws_size < need || nb > 1024 || n_nodes >= (1 << 17)) {
        hipMemsetAsync(d_out, 0, (size_t)out_size * sizeof(float), stream);
        const long long tt = (long long)nnz * 16;
        spmm_coo_atomic<<<(unsigned)((tt + 255) / 256), 256, 0, stream>>>(
            features, rows, cols, vals, out, nnz);
        return;
    }

    int*  gcnt   = (int*) (base + off_gcnt);
    int*  bptr   = (int*) (base + off_bptr);
    int*  cursor = (int*) (base + off_cursor);
    int2* edges  = (int2*)(base + off_edges);

    hipMemsetAsync(gcnt, 0, (size_t)nb * 4, stream);

    const int eb = (nnz + SBLK * EPT - 1) / (SBLK * EPT);
    hist_bucket<<<eb, SBLK, (size_t)nb * 4, stream>>>(rows, gcnt, nnz, nb);
    scan_small<<<1, 1024, 0, stream>>>(gcnt, bptr, cursor, nb);
    scatter_bucket<<<eb, SBLK, (size_t)2 * nb * 4, stream>>>(
        rows, cols, vals, cursor, edges, nnz, nb);
    spmm_bucket2<<<nb, 512, 0, stream>>>(features, edges, bptr, out, n_nodes);
}